// Round 1
// baseline (471.382 us; speedup 1.0000x reference)
//
#include <hip/hip_runtime.h>
#include <math.h>

// HashGrid: 8 LODs, hashed trilinear interp, 1 feature/entry, summed over LODs.
// LODS   = [17, 27, 44, 71, 116, 191, 313, res7(512 or 513 - host-computed)]
// SIZES  = [4913, 19683, 85184, 357911, 2^19, 2^19, 2^19, 2^19]
// codebook layout: [8][524288][1] float32.

static constexpr unsigned CB_STRIDE = 524288u;
static constexpr int SM0 = 4913;   // 17^3 floats, 19.2 KB
static constexpr int SM1 = 19683;  // 27^3 floats, 76.9 KB  (total LDS 98.4 KB)

template <unsigned SIZE, bool POW2>
__device__ __forceinline__ float lod_interp(float p01x, float p01y, float p01z,
                                            const float* table, int res)
{
    const float rm1 = (float)(res - 1);
    float xx = p01x * rm1, yy = p01y * rm1, zz = p01z * rm1;
    float fx = floorf(xx), fy = floorf(yy), fz = floorf(zz);
    const float cmax = (float)(res - 2);
    fx = fminf(fmaxf(fx, 0.0f), cmax);
    fy = fminf(fmaxf(fy, 0.0f), cmax);
    fz = fminf(fmaxf(fz, 0.0f), cmax);
    const float frx = xx - fx, fry = yy - fy, frz = zz - fz;
    const unsigned ix = (unsigned)(int)fx;
    const unsigned iy = (unsigned)(int)fy;
    const unsigned iz = (unsigned)(int)fz;

    // hash pieces: (c+1)*P = c*P + P
    const unsigned hx0 = ix;                  // PRIME0 = 1
    const unsigned hx1 = ix + 1u;
    const unsigned hy0 = iy * 2654435761u;
    const unsigned hy1 = hy0 + 2654435761u;
    const unsigned hz0 = iz * 805459861u;
    const unsigned hz1 = hz0 + 805459861u;

    unsigned i000 = hx0 ^ hy0 ^ hz0;
    unsigned i001 = hx0 ^ hy0 ^ hz1;
    unsigned i010 = hx0 ^ hy1 ^ hz0;
    unsigned i011 = hx0 ^ hy1 ^ hz1;
    unsigned i100 = hx1 ^ hy0 ^ hz0;
    unsigned i101 = hx1 ^ hy0 ^ hz1;
    unsigned i110 = hx1 ^ hy1 ^ hz0;
    unsigned i111 = hx1 ^ hy1 ^ hz1;

    if (POW2) {
        const unsigned m = SIZE - 1u;
        i000 &= m; i001 &= m; i010 &= m; i011 &= m;
        i100 &= m; i101 &= m; i110 &= m; i111 &= m;
    } else {
        i000 %= SIZE; i001 %= SIZE; i010 %= SIZE; i011 %= SIZE;
        i100 %= SIZE; i101 %= SIZE; i110 %= SIZE; i111 %= SIZE;
    }

    // issue all 8 loads before consuming (MLP)
    const float t000 = table[i000];
    const float t001 = table[i001];
    const float t010 = table[i010];
    const float t011 = table[i011];
    const float t100 = table[i100];
    const float t101 = table[i101];
    const float t110 = table[i110];
    const float t111 = table[i111];

    const float wx1 = frx, wx0 = 1.0f - frx;
    const float wy1 = fry, wy0 = 1.0f - fry;
    const float wz1 = frz, wz0 = 1.0f - frz;
    const float w00 = wy0 * wz0, w01 = wy0 * wz1;
    const float w10 = wy1 * wz0, w11 = wy1 * wz1;
    const float sx0 = t000 * w00 + t001 * w01 + t010 * w10 + t011 * w11;
    const float sx1 = t100 * w00 + t101 * w01 + t110 * w10 + t111 * w11;
    return wx0 * sx0 + wx1 * sx1;
}

__global__ __launch_bounds__(1024, 4)
void HashGrid_88278757802387_kernel(const float* __restrict__ pts,
                                    const float* __restrict__ codebook,
                                    float* __restrict__ out,
                                    int n, int res7)
{
    __shared__ float sm[SM0 + SM1];
    // stage LOD0 + LOD1 tables into LDS (cooperative, coalesced)
    for (int j = threadIdx.x; j < SM0; j += 1024) sm[j] = codebook[j];
    {
        const float* cb1 = codebook + CB_STRIDE;
        for (int j = threadIdx.x; j < SM1; j += 1024) sm[SM0 + j] = cb1[j];
    }
    __syncthreads();

    const int i = blockIdx.x * 1024 + threadIdx.x;
    if (i >= n) return;

    const float px = pts[3 * i + 0];
    const float py = pts[3 * i + 1];
    const float pz = pts[3 * i + 2];
    const float p01x = px * 0.5f + 0.5f;
    const float p01y = py * 0.5f + 0.5f;
    const float p01z = pz * 0.5f + 0.5f;

    float acc = 0.0f;
    // LOD0/1 from LDS
    acc += lod_interp<4913u,   false>(p01x, p01y, p01z, sm,        17);
    acc += lod_interp<19683u,  false>(p01x, p01y, p01z, sm + SM0,  27);
    // LOD2..7 from global (L1/L2/LLC)
    acc += lod_interp<85184u,  false>(p01x, p01y, p01z, codebook + 2u * CB_STRIDE, 44);
    acc += lod_interp<357911u, false>(p01x, p01y, p01z, codebook + 3u * CB_STRIDE, 71);
    acc += lod_interp<524288u, true >(p01x, p01y, p01z, codebook + 4u * CB_STRIDE, 116);
    acc += lod_interp<524288u, true >(p01x, p01y, p01z, codebook + 5u * CB_STRIDE, 191);
    acc += lod_interp<524288u, true >(p01x, p01y, p01z, codebook + 6u * CB_STRIDE, 313);
    acc += lod_interp<524288u, true >(p01x, p01y, p01z, codebook + 7u * CB_STRIDE, res7);

    out[i] = acc;
}

extern "C" void kernel_launch(void* const* d_in, const int* in_sizes, int n_in,
                              void* d_out, int out_size, void* d_ws, size_t ws_size,
                              hipStream_t stream)
{
    const float* pts      = (const float*)d_in[0];
    const float* codebook = (const float*)d_in[1];
    float* out            = (float*)d_out;
    const int n = in_sizes[0] / 3;

    // Replicate numpy's double-precision LOD computation for the boundary case
    // l=7: 16*b^7 is within ~1e-12 of 512.0; trust libm to match numpy here.
    const double b = exp((log(512.0) - log(16.0)) / 7.0);
    const int res7 = (int)(1.0 + floor(16.0 * pow(b, 7.0)));

    const int blocks = (n + 1023) / 1024;
    hipLaunchKernelGGL(HashGrid_88278757802387_kernel, dim3(blocks), dim3(1024),
                       0, stream, pts, codebook, out, n, res7);
}

// Round 2
// 413.532 us; speedup vs baseline: 1.1399x; 1.1399x over previous
//
#include <hip/hip_runtime.h>
#include <math.h>

// HashGrid: 8 LODs, hashed trilinear interp, 1 feature/entry, summed over LODs.
// LODS  = [17, 27, 44, 71, 116, 191, 313, res7(host-computed, 512 or 513)]
// SIZES = [4913, 19683, 85184, 357911, 2^19, 2^19, 2^19, 2^19]
// codebook layout: [8][524288][1] float32.
//
// R2 strategy: bf16 everywhere on the gather path.
//  - LOD0+LOD1 staged to LDS as bf16 (49.2 KB -> 2 blocks/CU -> 32 waves/CU).
//  - LOD2..7 converted once per call to bf16 in d_ws (5.08 MB total -> fits
//    per-XCD L2 far better than 9.8 MB f32 -> higher L2 hit rate on random
//    gathers). Falls back to f32-from-codebook if ws_size is too small.

static constexpr unsigned CB_STRIDE = 524288u;
static constexpr int S0 = 4913;    // 17^3
static constexpr int S1 = 19683;   // 27^3
// ws (bf16) element offsets for LOD2..7, 32-elem aligned
static constexpr int WO2 = 0;        // 85184
static constexpr int WO3 = 85184;    // 357911
static constexpr int WO4 = 443104;   // 524288
static constexpr int WO5 = 967392;
static constexpr int WO6 = 1491680;
static constexpr int WO7 = 2015968;
static constexpr size_t WS_NEED_BYTES = 2540256u * 2u;  // 5.08 MB

__device__ __forceinline__ unsigned short f32_to_bf16_rne(float f) {
    unsigned u = __float_as_uint(f);
    u = (u + 0x7FFFu + ((u >> 16) & 1u)) >> 16;
    return (unsigned short)u;
}
__device__ __forceinline__ float bf16_to_f32(unsigned short s) {
    return __uint_as_float(((unsigned)s) << 16);
}

template <typename T>
__device__ __forceinline__ float ld_tab(const T* t, unsigned i);
template <> __device__ __forceinline__ float ld_tab<float>(const float* t, unsigned i) { return t[i]; }
template <> __device__ __forceinline__ float ld_tab<unsigned short>(const unsigned short* t, unsigned i) { return bf16_to_f32(t[i]); }

template <unsigned SIZE, bool POW2, typename T>
__device__ __forceinline__ float lod_interp(float p01x, float p01y, float p01z,
                                            const T* __restrict__ table, int res)
{
    const float rm1 = (float)(res - 1);
    float xx = p01x * rm1, yy = p01y * rm1, zz = p01z * rm1;
    float fx = floorf(xx), fy = floorf(yy), fz = floorf(zz);
    const float cmax = (float)(res - 2);
    fx = fminf(fmaxf(fx, 0.0f), cmax);
    fy = fminf(fmaxf(fy, 0.0f), cmax);
    fz = fminf(fmaxf(fz, 0.0f), cmax);
    const float frx = xx - fx, fry = yy - fy, frz = zz - fz;
    const unsigned ix = (unsigned)(int)fx;
    const unsigned iy = (unsigned)(int)fy;
    const unsigned iz = (unsigned)(int)fz;

    const unsigned hx0 = ix;                  // PRIME0 = 1
    const unsigned hx1 = ix + 1u;
    const unsigned hy0 = iy * 2654435761u;
    const unsigned hy1 = hy0 + 2654435761u;
    const unsigned hz0 = iz * 805459861u;
    const unsigned hz1 = hz0 + 805459861u;

    unsigned i000 = hx0 ^ hy0 ^ hz0;
    unsigned i001 = hx0 ^ hy0 ^ hz1;
    unsigned i010 = hx0 ^ hy1 ^ hz0;
    unsigned i011 = hx0 ^ hy1 ^ hz1;
    unsigned i100 = hx1 ^ hy0 ^ hz0;
    unsigned i101 = hx1 ^ hy0 ^ hz1;
    unsigned i110 = hx1 ^ hy1 ^ hz0;
    unsigned i111 = hx1 ^ hy1 ^ hz1;

    if (POW2) {
        const unsigned m = SIZE - 1u;
        i000 &= m; i001 &= m; i010 &= m; i011 &= m;
        i100 &= m; i101 &= m; i110 &= m; i111 &= m;
    } else {
        i000 %= SIZE; i001 %= SIZE; i010 %= SIZE; i011 %= SIZE;
        i100 %= SIZE; i101 %= SIZE; i110 %= SIZE; i111 %= SIZE;
    }

    const float t000 = ld_tab(table, i000);
    const float t001 = ld_tab(table, i001);
    const float t010 = ld_tab(table, i010);
    const float t011 = ld_tab(table, i011);
    const float t100 = ld_tab(table, i100);
    const float t101 = ld_tab(table, i101);
    const float t110 = ld_tab(table, i110);
    const float t111 = ld_tab(table, i111);

    const float wx1 = frx, wx0 = 1.0f - frx;
    const float wy1 = fry, wy0 = 1.0f - fry;
    const float wz1 = frz, wz0 = 1.0f - frz;
    const float w00 = wy0 * wz0, w01 = wy0 * wz1;
    const float w10 = wy1 * wz0, w11 = wy1 * wz1;
    const float sx0 = t000 * w00 + t001 * w01 + t010 * w10 + t011 * w11;
    const float sx1 = t100 * w00 + t101 * w01 + t110 * w10 + t111 * w11;
    return wx0 * sx0 + wx1 * sx1;
}

// prep: convert LOD2..7 table prefixes to bf16 in ws
__global__ __launch_bounds__(1024)
void HashGrid_convert_kernel(const float* __restrict__ codebook,
                             unsigned short* __restrict__ ws)
{
    const int lod = blockIdx.y;  // 0..5 -> LOD2..7
    const int sizes[6] = {85184, 357911, 524288, 524288, 524288, 524288};
    const int offs[6]  = {WO2, WO3, WO4, WO5, WO6, WO7};
    const int idx = blockIdx.x * 1024 + threadIdx.x;
    if (idx < sizes[lod])
        ws[offs[lod] + idx] = f32_to_bf16_rne(codebook[(unsigned)(lod + 2) * CB_STRIDE + idx]);
}

template <bool GBF16>
__global__ __launch_bounds__(1024, 8)
void HashGrid_88278757802387_kernel(const float* __restrict__ pts,
                                    const float* __restrict__ codebook,
                                    const unsigned short* __restrict__ ws,
                                    float* __restrict__ out,
                                    int n, int res7)
{
    __shared__ unsigned short sm[S0 + S1];  // 49.2 KB -> 2 blocks/CU
    for (int j = threadIdx.x; j < S0 + S1; j += 1024)
        sm[j] = f32_to_bf16_rne(j < S0 ? codebook[j] : codebook[CB_STRIDE + (j - S0)]);
    __syncthreads();

    const int i = blockIdx.x * 1024 + threadIdx.x;
    if (i >= n) return;

    const float p01x = pts[3 * i + 0] * 0.5f + 0.5f;
    const float p01y = pts[3 * i + 1] * 0.5f + 0.5f;
    const float p01z = pts[3 * i + 2] * 0.5f + 0.5f;

    float acc = 0.0f;
    acc += lod_interp<4913u,   false>(p01x, p01y, p01z, (const unsigned short*)sm,      17);
    acc += lod_interp<19683u,  false>(p01x, p01y, p01z, (const unsigned short*)sm + S0, 27);
    if (GBF16) {
        acc += lod_interp<85184u,  false>(p01x, p01y, p01z, ws + WO2, 44);
        acc += lod_interp<357911u, false>(p01x, p01y, p01z, ws + WO3, 71);
        acc += lod_interp<524288u, true >(p01x, p01y, p01z, ws + WO4, 116);
        acc += lod_interp<524288u, true >(p01x, p01y, p01z, ws + WO5, 191);
        acc += lod_interp<524288u, true >(p01x, p01y, p01z, ws + WO6, 313);
        acc += lod_interp<524288u, true >(p01x, p01y, p01z, ws + WO7, res7);
    } else {
        acc += lod_interp<85184u,  false>(p01x, p01y, p01z, codebook + 2u * CB_STRIDE, 44);
        acc += lod_interp<357911u, false>(p01x, p01y, p01z, codebook + 3u * CB_STRIDE, 71);
        acc += lod_interp<524288u, true >(p01x, p01y, p01z, codebook + 4u * CB_STRIDE, 116);
        acc += lod_interp<524288u, true >(p01x, p01y, p01z, codebook + 5u * CB_STRIDE, 191);
        acc += lod_interp<524288u, true >(p01x, p01y, p01z, codebook + 6u * CB_STRIDE, 313);
        acc += lod_interp<524288u, true >(p01x, p01y, p01z, codebook + 7u * CB_STRIDE, res7);
    }

    out[i] = acc;
}

extern "C" void kernel_launch(void* const* d_in, const int* in_sizes, int n_in,
                              void* d_out, int out_size, void* d_ws, size_t ws_size,
                              hipStream_t stream)
{
    const float* pts      = (const float*)d_in[0];
    const float* codebook = (const float*)d_in[1];
    float* out            = (float*)d_out;
    const int n = in_sizes[0] / 3;

    // numpy-matching LOD7 resolution (16*b^7 sits ~1e-12 below/above 512.0)
    const double b = exp((log(512.0) - log(16.0)) / 7.0);
    const int res7 = (int)(1.0 + floor(16.0 * pow(b, 7.0)));

    const bool use_ws = (d_ws != nullptr) && (ws_size >= WS_NEED_BYTES);
    const int blocks = (n + 1023) / 1024;

    if (use_ws) {
        unsigned short* ws = (unsigned short*)d_ws;
        hipLaunchKernelGGL(HashGrid_convert_kernel, dim3(512, 6), dim3(1024),
                           0, stream, codebook, ws);
        hipLaunchKernelGGL(HashGrid_88278757802387_kernel<true>, dim3(blocks), dim3(1024),
                           0, stream, pts, codebook, ws, out, n, res7);
    } else {
        hipLaunchKernelGGL(HashGrid_88278757802387_kernel<false>, dim3(blocks), dim3(1024),
                           0, stream, pts, codebook, (const unsigned short*)nullptr, out, n, res7);
    }
}